// Round 6
// baseline (639.328 us; speedup 1.0000x reference)
//
#include <hip/hip_runtime.h>
#include <stdint.h>

#define N_ 8192
#define D_ 1024
// logit = dot(imn,capn)/T; fp8 operands pre-scaled by 16 -> acc = 256*dot
#define EPILOGUE_SCALE (10.0f / 256.0f)
#define ENC_SCALE 16.0f
#define SCALE_1 0x7F7F7F7Fu  // e8m0 1.0 in every byte (MX scales disabled)

typedef float f32x4 __attribute__((ext_vector_type(4)));
typedef int i32x8 __attribute__((ext_vector_type(8)));

// MX-K128 swizzled fragment layout (both operands), 8 MB each.
// 8 slabs (s = K/128), 512 tiles of 16 rows, per tile-slab block 2048 B
// (512 dwords), dword index:
//   idx = s*262144 + til*512 + h*256 + fl*4 + q     (h in {0,1}, fl in [0,64))
//   holds row = til*16 + (fl&15),
//         k-dword (abs) = s*32 + (fl>>4)*8 + h*4 + q
// GEMM lane l reads dwordx4 at dword (blk + l*4) and (blk + 256 + l*4):
// together = 32 consecutive k-bytes for m = l&15, kg = l>>4 -> matches the
// 16x16 A/B operand layout (m = lane&15, k = (lane>>4)*32 + 0..31).
// Each dwordx4 instr covers a contiguous 1 kB (perfect coalescing).

// Kernel 1: one 16-row tile per block. Phase 1: norms + diag. Phase 2: convert
// to fp8 via LDS. Phase 3: fully-coalesced uint4 stores in MX fragment order.
// Blocks 0..15 also zero rowsum/colsum (replaces memset dispatch).
__global__ __launch_bounds__(256) void normalize_k(
    const float* __restrict__ im, const float* __restrict__ cap,
    unsigned int* __restrict__ imn, unsigned int* __restrict__ capn,
    float* __restrict__ diag, float* __restrict__ sums /* rowsum|colsum */) {
  __shared__ unsigned int ldsA[16 * 257];
  __shared__ unsigned int ldsB[16 * 257];
  const int til = blockIdx.x;
  const int t = threadIdx.x;
  if (til < 16) ((float4*)sums)[til * 256 + t] = (float4){0.f, 0.f, 0.f, 0.f};

  const int rloc = t >> 4, j = t & 15;
  const int row = til * 16 + rloc;
  const float4* __restrict__ aR = (const float4*)(im + (size_t)row * D_);
  const float4* __restrict__ bR = (const float4*)(cap + (size_t)row * D_);

  float ssa = 0.f, ssb = 0.f, dt = 0.f;
#pragma unroll
  for (int i = 0; i < 16; ++i) {
    const float4 a = aR[j + 16 * i];
    const float4 b = bR[j + 16 * i];
    ssa += a.x * a.x + a.y * a.y + a.z * a.z + a.w * a.w;
    ssb += b.x * b.x + b.y * b.y + b.z * b.z + b.w * b.w;
    dt  += a.x * b.x + a.y * b.y + a.z * b.z + a.w * b.w;
  }
#pragma unroll
  for (int o = 1; o < 16; o <<= 1) {  // reduce across the 16 lanes of this row
    ssa += __shfl_xor(ssa, o, 64);
    ssb += __shfl_xor(ssb, o, 64);
    dt  += __shfl_xor(dt, o, 64);
  }
  const float ra = rsqrtf(ssa), rb = rsqrtf(ssb);
  if (j == 0) diag[row] = dt * ra * rb * 10.0f;
  const float sa = ra * ENC_SCALE, sb = rb * ENC_SCALE;

  // phase 2: re-read (L1/L2 hot), convert, stage in LDS [row][k-dword]
#pragma unroll
  for (int i = 0; i < 16; ++i) {
    const float4 a = aR[j + 16 * i];
    const float4 b = bR[j + 16 * i];
    int pa = __builtin_amdgcn_cvt_pk_fp8_f32(a.x * sa, a.y * sa, 0, false);
    pa = __builtin_amdgcn_cvt_pk_fp8_f32(a.z * sa, a.w * sa, pa, true);
    int pb = __builtin_amdgcn_cvt_pk_fp8_f32(b.x * sb, b.y * sb, 0, false);
    pb = __builtin_amdgcn_cvt_pk_fp8_f32(b.z * sb, b.w * sb, pb, true);
    ldsA[rloc * 257 + j + 16 * i] = (unsigned int)pa;
    ldsB[rloc * 257 + j + 16 * i] = (unsigned int)pb;
  }
  __syncthreads();

  // phase 3: coalesced MX-fragment-order stores, 4 uint4 chunks per thread
#pragma unroll
  for (int i = 0; i < 4; ++i) {
    const int cid = i * 256 + t;          // 1024 chunks
    const int s = cid >> 7, rem = cid & 127;
    const int h = rem >> 6, fl = rem & 63;
    const int m15 = fl & 15, kg = fl >> 4;
    const int p0 = s * 32 + kg * 8 + h * 4;   // k-dword base for this chunk
    uint4 va, vb;
#pragma unroll
    for (int q = 0; q < 4; ++q) {
      ((unsigned int*)&va)[q] = ldsA[m15 * 257 + p0 + q];
      ((unsigned int*)&vb)[q] = ldsB[m15 * 257 + p0 + q];
    }
    const size_t d = (size_t)s * 262144 + (size_t)til * 512 + rem * 4;
    *(uint4*)(imn + d) = va;
    *(uint4*)(capn + d) = vb;
  }
}

// Kernel 2: no-LDS, no-barrier MX-fp8 GEMM (K=128 per MFMA, scales = 1.0)
// + exp + row/col partial sums. 128x128 block tile, 4 waves each a 64x64
// quadrant of 4x4 16x16x128 MFMA tiles. 8 K-slabs, depth-2 prefetch; each
// slab is ~550 SIMD-cycles of MFMA -> L3 latency fits inside the window.
__global__ __launch_bounds__(256, 2) void gemm_lse_k(
    const unsigned char* __restrict__ A,   // swizzled imn
    const unsigned char* __restrict__ B,   // swizzled capn
    float* __restrict__ rowsum, float* __restrict__ colsum) {
  const int t = threadIdx.x;
  const int w = t >> 6, l = t & 63;
  const int rowBase = blockIdx.x * 128;
  const int colBase = blockIdx.y * 128;
  const int wq_m = (w >> 1) * 64, wq_n = (w & 1) * 64;

  // byte offsets of the lo/hi dwordx4 for each of this wave's 4 A / 4 B tiles
  unsigned offA[4], offB[4];
#pragma unroll
  for (int i = 0; i < 4; ++i) {
    offA[i] = (unsigned)((blockIdx.x * 8 + (w >> 1) * 4 + i) * 2048 + l * 16);
    offB[i] = (unsigned)((blockIdx.y * 8 + (w & 1) * 4 + i) * 2048 + l * 16);
  }

  f32x4 acc[4][4];
#pragma unroll
  for (int i = 0; i < 4; ++i)
#pragma unroll
    for (int j = 0; j < 4; ++j)
      acc[i][j] = (f32x4){0.f, 0.f, 0.f, 0.f};

  // stage buffers: [st][0..3]=A lo, [4..7]=A hi, [8..11]=B lo, [12..15]=B hi
  uint4 stg[2][16];
#pragma unroll
  for (int i = 0; i < 4; ++i) {  // preload slab 0
    stg[0][i]      = *(const uint4*)(A + offA[i]);
    stg[0][4 + i]  = *(const uint4*)(A + offA[i] + 1024);
    stg[0][8 + i]  = *(const uint4*)(B + offB[i]);
    stg[0][12 + i] = *(const uint4*)(B + offB[i] + 1024);
  }

#pragma unroll
  for (int s = 0; s < 8; ++s) {
    const int cur = s & 1, nxt = cur ^ 1;
    if (s + 1 < 8) {  // prefetch slab s+1
      const unsigned char* pA = A + (size_t)(s + 1) * 1048576;
      const unsigned char* pB = B + (size_t)(s + 1) * 1048576;
#pragma unroll
      for (int i = 0; i < 4; ++i) {
        stg[nxt][i]      = *(const uint4*)(pA + offA[i]);
        stg[nxt][4 + i]  = *(const uint4*)(pA + offA[i] + 1024);
        stg[nxt][8 + i]  = *(const uint4*)(pB + offB[i]);
        stg[nxt][12 + i] = *(const uint4*)(pB + offB[i] + 1024);
      }
    }
#pragma unroll
    for (int mt = 0; mt < 4; ++mt) {
      i32x8 af;
#pragma unroll
      for (int q = 0; q < 4; ++q) {
        af[q]     = (int)((const unsigned int*)&stg[cur][mt])[q];
        af[4 + q] = (int)((const unsigned int*)&stg[cur][4 + mt])[q];
      }
#pragma unroll
      for (int nt = 0; nt < 4; ++nt) {
        i32x8 bf;
#pragma unroll
        for (int q = 0; q < 4; ++q) {
          bf[q]     = (int)((const unsigned int*)&stg[cur][8 + nt])[q];
          bf[4 + q] = (int)((const unsigned int*)&stg[cur][12 + nt])[q];
        }
        acc[mt][nt] = __builtin_amdgcn_mfma_scale_f32_16x16x128_f8f6f4(
            af, bf, acc[mt][nt], 0, 0, 0, SCALE_1, 0, SCALE_1);
      }
    }
  }

  // epilogue: exp (fixed-max LSE; |logit| <= 10, no overflow possible)
#pragma unroll
  for (int mt = 0; mt < 4; ++mt)
#pragma unroll
    for (int nt = 0; nt < 4; ++nt)
#pragma unroll
      for (int r = 0; r < 4; ++r)
        acc[mt][nt][r] = __expf(acc[mt][nt][r] * EPILOGUE_SCALE);

  // C/D layout: col = lane&15, row = (lane>>4)*4 + reg  [measured m89/m91;
  // shape-determined, dtype/format-independent — m121..m128]
#pragma unroll
  for (int mt = 0; mt < 4; ++mt)
#pragma unroll
    for (int r = 0; r < 4; ++r) {
      float v = acc[mt][0][r] + acc[mt][1][r] + acc[mt][2][r] + acc[mt][3][r];
      v += __shfl_xor(v, 1, 64);
      v += __shfl_xor(v, 2, 64);
      v += __shfl_xor(v, 4, 64);
      v += __shfl_xor(v, 8, 64);
      if ((l & 15) == 0)
        atomicAdd(&rowsum[rowBase + wq_m + mt * 16 + (l >> 4) * 4 + r], v);
    }
#pragma unroll
  for (int nt = 0; nt < 4; ++nt) {
    float v = 0.f;
#pragma unroll
    for (int mt = 0; mt < 4; ++mt)
      v += acc[mt][nt][0] + acc[mt][nt][1] + acc[mt][nt][2] + acc[mt][nt][3];
    v += __shfl_xor(v, 16, 64);
    v += __shfl_xor(v, 32, 64);
    if (l < 16)
      atomicAdd(&colsum[colBase + wq_n + nt * 16 + l], v);
  }
}

// Kernel 3: scalar reduce.
__global__ __launch_bounds__(256) void finalize_k(
    const float* __restrict__ rowsum, const float* __restrict__ colsum,
    const float* __restrict__ diag, float* __restrict__ out) {
  const int t = threadIdx.x;
  float lse = 0.f, dg = 0.f;
  for (int i = t; i < N_; i += 256) {
    lse += __logf(rowsum[i]) + __logf(colsum[i]);
    dg += diag[i];
  }
#pragma unroll
  for (int o = 32; o > 0; o >>= 1) {
    lse += __shfl_down(lse, o, 64);
    dg  += __shfl_down(dg, o, 64);
  }
  __shared__ float red[2][4];
  const int w = t >> 6, l = t & 63;
  if (l == 0) { red[0][w] = lse; red[1][w] = dg; }
  __syncthreads();
  if (t == 0) {
    lse = red[0][0] + red[0][1] + red[0][2] + red[0][3];
    dg  = red[1][0] + red[1][1] + red[1][2] + red[1][3];
    out[0] = 0.5f * lse / (float)N_ - dg / (float)N_;
  }
}

extern "C" void kernel_launch(void* const* d_in, const int* in_sizes, int n_in,
                              void* d_out, int out_size, void* d_ws, size_t ws_size,
                              hipStream_t stream) {
  const float* im = (const float*)d_in[0];
  const float* cap = (const float*)d_in[1];
  float* out = (float*)d_out;
  char* ws = (char*)d_ws;
  unsigned char* imn = (unsigned char*)ws;                 // 8 MB fp8 (MX swizzled)
  unsigned char* capn = imn + (size_t)N_ * D_;             // 8 MB fp8 (MX swizzled)
  float* rowsum = (float*)(ws + 2 * (size_t)N_ * D_);
  float* colsum = rowsum + N_;
  float* diag = colsum + N_;

  normalize_k<<<512, 256, 0, stream>>>(im, cap, (unsigned int*)imn,
                                       (unsigned int*)capn, diag, rowsum);
  gemm_lse_k<<<dim3(64, 64), 256, 0, stream>>>(imn, capn, rowsum, colsum);
  finalize_k<<<1, 256, 0, stream>>>(rowsum, colsum, diag, out);
}

// Round 7
// 575.850 us; speedup vs baseline: 1.1102x; 1.1102x over previous
//
#include <hip/hip_runtime.h>
#include <stdint.h>

#define N_ 8192
#define D_ 1024
// logit = dot(imn,capn)/T; fp8 operands pre-scaled by 16 -> acc = 256*dot
#define EPILOGUE_SCALE (10.0f / 256.0f)
#define ENC_SCALE 16.0f
#define SCALE_1 0x7F7F7F7Fu  // e8m0 1.0 in every byte (MX scales disabled)

typedef float f32x4 __attribute__((ext_vector_type(4)));
typedef int i32x8 __attribute__((ext_vector_type(8)));

// MX-K128 swizzled fragment layout (both operands), 8 MB each.
// 8 slabs (s = K/128), 512 tiles of 16 rows, per tile-slab block 2048 B
// (512 dwords), dword index:
//   idx = s*262144 + til*512 + h*256 + fl*4 + q     (h in {0,1}, fl in [0,64))
//   holds row = til*16 + (fl&15),
//         k-dword (abs) = s*32 + (fl>>4)*8 + h*4 + q
// GEMM lane l reads dwordx4 at dword (blk + l*4) and (blk + 256 + l*4):
// together = 32 consecutive k-bytes for m = l&15, kg = l>>4 -> matches the
// 16x16 A/B operand layout (m = lane&15, k = (lane>>4)*32 + 0..31).
// Each dwordx4 instr covers a contiguous 1 kB (perfect coalescing).

// Kernel 1: one 16-row tile per block. Phase 1: norms + diag. Phase 2: convert
// to fp8 via LDS. Phase 3: fully-coalesced uint4 stores in MX fragment order.
// Blocks 0..15 also zero rowsum/colsum (replaces memset dispatch).
__global__ __launch_bounds__(256) void normalize_k(
    const float* __restrict__ im, const float* __restrict__ cap,
    unsigned int* __restrict__ imn, unsigned int* __restrict__ capn,
    float* __restrict__ diag, float* __restrict__ sums /* rowsum|colsum */) {
  __shared__ unsigned int ldsA[16 * 257];
  __shared__ unsigned int ldsB[16 * 257];
  const int til = blockIdx.x;
  const int t = threadIdx.x;
  if (til < 16) ((float4*)sums)[til * 256 + t] = (float4){0.f, 0.f, 0.f, 0.f};

  const int rloc = t >> 4, j = t & 15;
  const int row = til * 16 + rloc;
  const float4* __restrict__ aR = (const float4*)(im + (size_t)row * D_);
  const float4* __restrict__ bR = (const float4*)(cap + (size_t)row * D_);

  float ssa = 0.f, ssb = 0.f, dt = 0.f;
#pragma unroll
  for (int i = 0; i < 16; ++i) {
    const float4 a = aR[j + 16 * i];
    const float4 b = bR[j + 16 * i];
    ssa += a.x * a.x + a.y * a.y + a.z * a.z + a.w * a.w;
    ssb += b.x * b.x + b.y * b.y + b.z * b.z + b.w * b.w;
    dt  += a.x * b.x + a.y * b.y + a.z * b.z + a.w * b.w;
  }
#pragma unroll
  for (int o = 1; o < 16; o <<= 1) {  // reduce across the 16 lanes of this row
    ssa += __shfl_xor(ssa, o, 64);
    ssb += __shfl_xor(ssb, o, 64);
    dt  += __shfl_xor(dt, o, 64);
  }
  const float ra = rsqrtf(ssa), rb = rsqrtf(ssb);
  if (j == 0) diag[row] = dt * ra * rb * 10.0f;
  const float sa = ra * ENC_SCALE, sb = rb * ENC_SCALE;

  // phase 2: re-read (L1/L2 hot), convert, stage in LDS [row][k-dword]
#pragma unroll
  for (int i = 0; i < 16; ++i) {
    const float4 a = aR[j + 16 * i];
    const float4 b = bR[j + 16 * i];
    int pa = __builtin_amdgcn_cvt_pk_fp8_f32(a.x * sa, a.y * sa, 0, false);
    pa = __builtin_amdgcn_cvt_pk_fp8_f32(a.z * sa, a.w * sa, pa, true);
    int pb = __builtin_amdgcn_cvt_pk_fp8_f32(b.x * sb, b.y * sb, 0, false);
    pb = __builtin_amdgcn_cvt_pk_fp8_f32(b.z * sb, b.w * sb, pb, true);
    ldsA[rloc * 257 + j + 16 * i] = (unsigned int)pa;
    ldsB[rloc * 257 + j + 16 * i] = (unsigned int)pb;
  }
  __syncthreads();

  // phase 3: coalesced MX-fragment-order stores, 4 uint4 chunks per thread
#pragma unroll
  for (int i = 0; i < 4; ++i) {
    const int cid = i * 256 + t;          // 1024 chunks
    const int s = cid >> 7, rem = cid & 127;
    const int h = rem >> 6, fl = rem & 63;
    const int m15 = fl & 15, kg = fl >> 4;
    const int p0 = s * 32 + kg * 8 + h * 4;   // k-dword base for this chunk
    uint4 va, vb;
#pragma unroll
    for (int q = 0; q < 4; ++q) {
      ((unsigned int*)&va)[q] = ldsA[m15 * 257 + p0 + q];
      ((unsigned int*)&vb)[q] = ldsB[m15 * 257 + p0 + q];
    }
    const size_t d = (size_t)s * 262144 + (size_t)til * 512 + rem * 4;
    *(uint4*)(imn + d) = va;
    *(uint4*)(capn + d) = vb;
  }
}

// helper: load one K=128 operand fragment (two contiguous-1kB dwordx4 pulls)
__device__ __forceinline__ i32x8 ld_frag(const unsigned char* base, unsigned off) {
  i32x8 r;
  ((uint4*)&r)[0] = *(const uint4*)(base + off);
  ((uint4*)&r)[1] = *(const uint4*)(base + off + 1024);
  return r;
}

// Kernel 2: no-LDS, no-barrier MX-fp8 GEMM (K=128 per MFMA, scales = 1.0)
// + exp + row/col partial sums. 128x128 block tile, 4 waves each a 64x64
// quadrant of 4x4 16x16x128 MFMA tiles. 8 K-slabs, explicit NAMED
// double-buffer (no indexable local array -> no scratch; R6's stg[2][16]
// spilled 2.1 GB to scratch and ran 3x slower).
__global__ __launch_bounds__(256, 2) void gemm_lse_k(
    const unsigned char* __restrict__ A,   // swizzled imn
    const unsigned char* __restrict__ B,   // swizzled capn
    float* __restrict__ rowsum, float* __restrict__ colsum) {
  const int t = threadIdx.x;
  const int w = t >> 6, l = t & 63;
  const int rowBase = blockIdx.x * 128;
  const int colBase = blockIdx.y * 128;
  const int wq_m = (w >> 1) * 64, wq_n = (w & 1) * 64;

  unsigned offA[4], offB[4];
#pragma unroll
  for (int i = 0; i < 4; ++i) {
    offA[i] = (unsigned)((blockIdx.x * 8 + (w >> 1) * 4 + i) * 2048 + l * 16);
    offB[i] = (unsigned)((blockIdx.y * 8 + (w & 1) * 4 + i) * 2048 + l * 16);
  }

  f32x4 acc[4][4];
#pragma unroll
  for (int i = 0; i < 4; ++i)
#pragma unroll
    for (int j = 0; j < 4; ++j)
      acc[i][j] = (f32x4){0.f, 0.f, 0.f, 0.f};

  i32x8 a0[4], b0[4], a1[4], b1[4];
#pragma unroll
  for (int i = 0; i < 4; ++i) {  // preload slab 0
    a0[i] = ld_frag(A, offA[i]);
    b0[i] = ld_frag(B, offB[i]);
  }

#pragma unroll
  for (int s = 0; s < 8; s += 2) {
    {  // prefetch slab s+1
      const unsigned char* pA = A + (size_t)(s + 1) * 1048576;
      const unsigned char* pB = B + (size_t)(s + 1) * 1048576;
#pragma unroll
      for (int i = 0; i < 4; ++i) {
        a1[i] = ld_frag(pA, offA[i]);
        b1[i] = ld_frag(pB, offB[i]);
      }
    }
#pragma unroll
    for (int mt = 0; mt < 4; ++mt)
#pragma unroll
      for (int nt = 0; nt < 4; ++nt)
        acc[mt][nt] = __builtin_amdgcn_mfma_scale_f32_16x16x128_f8f6f4(
            a0[mt], b0[nt], acc[mt][nt], 0, 0, 0, SCALE_1, 0, SCALE_1);
    if (s + 2 < 8) {  // prefetch slab s+2
      const unsigned char* pA = A + (size_t)(s + 2) * 1048576;
      const unsigned char* pB = B + (size_t)(s + 2) * 1048576;
#pragma unroll
      for (int i = 0; i < 4; ++i) {
        a0[i] = ld_frag(pA, offA[i]);
        b0[i] = ld_frag(pB, offB[i]);
      }
    }
#pragma unroll
    for (int mt = 0; mt < 4; ++mt)
#pragma unroll
      for (int nt = 0; nt < 4; ++nt)
        acc[mt][nt] = __builtin_amdgcn_mfma_scale_f32_16x16x128_f8f6f4(
            a1[mt], b1[nt], acc[mt][nt], 0, 0, 0, SCALE_1, 0, SCALE_1);
  }

  // epilogue: exp (fixed-max LSE; |logit| <= 10, no overflow possible)
#pragma unroll
  for (int mt = 0; mt < 4; ++mt)
#pragma unroll
    for (int nt = 0; nt < 4; ++nt)
#pragma unroll
      for (int r = 0; r < 4; ++r)
        acc[mt][nt][r] = __expf(acc[mt][nt][r] * EPILOGUE_SCALE);

  // C/D layout: col = lane&15, row = (lane>>4)*4 + reg  [measured m89/m91;
  // shape-determined, dtype/format-independent — m121..m128]
#pragma unroll
  for (int mt = 0; mt < 4; ++mt)
#pragma unroll
    for (int r = 0; r < 4; ++r) {
      float v = acc[mt][0][r] + acc[mt][1][r] + acc[mt][2][r] + acc[mt][3][r];
      v += __shfl_xor(v, 1, 64);
      v += __shfl_xor(v, 2, 64);
      v += __shfl_xor(v, 4, 64);
      v += __shfl_xor(v, 8, 64);
      if ((l & 15) == 0)
        atomicAdd(&rowsum[rowBase + wq_m + mt * 16 + (l >> 4) * 4 + r], v);
    }
#pragma unroll
  for (int nt = 0; nt < 4; ++nt) {
    float v = 0.f;
#pragma unroll
    for (int mt = 0; mt < 4; ++mt)
      v += acc[mt][nt][0] + acc[mt][nt][1] + acc[mt][nt][2] + acc[mt][nt][3];
    v += __shfl_xor(v, 16, 64);
    v += __shfl_xor(v, 32, 64);
    if (l < 16)
      atomicAdd(&colsum[colBase + wq_n + nt * 16 + l], v);
  }
}

// Kernel 3: scalar reduce.
__global__ __launch_bounds__(256) void finalize_k(
    const float* __restrict__ rowsum, const float* __restrict__ colsum,
    const float* __restrict__ diag, float* __restrict__ out) {
  const int t = threadIdx.x;
  float lse = 0.f, dg = 0.f;
  for (int i = t; i < N_; i += 256) {
    lse += __logf(rowsum[i]) + __logf(colsum[i]);
    dg += diag[i];
  }
#pragma unroll
  for (int o = 32; o > 0; o >>= 1) {
    lse += __shfl_down(lse, o, 64);
    dg  += __shfl_down(dg, o, 64);
  }
  __shared__ float red[2][4];
  const int w = t >> 6, l = t & 63;
  if (l == 0) { red[0][w] = lse; red[1][w] = dg; }
  __syncthreads();
  if (t == 0) {
    lse = red[0][0] + red[0][1] + red[0][2] + red[0][3];
    dg  = red[1][0] + red[1][1] + red[1][2] + red[1][3];
    out[0] = 0.5f * lse / (float)N_ - dg / (float)N_;
  }
}

extern "C" void kernel_launch(void* const* d_in, const int* in_sizes, int n_in,
                              void* d_out, int out_size, void* d_ws, size_t ws_size,
                              hipStream_t stream) {
  const float* im = (const float*)d_in[0];
  const float* cap = (const float*)d_in[1];
  float* out = (float*)d_out;
  char* ws = (char*)d_ws;
  unsigned char* imn = (unsigned char*)ws;                 // 8 MB fp8 (MX swizzled)
  unsigned char* capn = imn + (size_t)N_ * D_;             // 8 MB fp8 (MX swizzled)
  float* rowsum = (float*)(ws + 2 * (size_t)N_ * D_);
  float* colsum = rowsum + N_;
  float* diag = colsum + N_;

  normalize_k<<<512, 256, 0, stream>>>(im, cap, (unsigned int*)imn,
                                       (unsigned int*)capn, diag, rowsum);
  gemm_lse_k<<<dim3(64, 64), 256, 0, stream>>>(imn, capn, rowsum, colsum);
  finalize_k<<<1, 256, 0, stream>>>(rowsum, colsum, diag, out);
}